// Round 15
// baseline (3442.386 us; speedup 1.0000x reference)
//
#include <hip/hip_runtime.h>
#include <cstdint>
#include <cstddef>

// ---------------- types / helpers ----------------
typedef __bf16 bf16x8 __attribute__((ext_vector_type(8)));
typedef float f32x4 __attribute__((ext_vector_type(4)));

__device__ __forceinline__ unsigned short f2bf(float f) {
  unsigned u = __float_as_uint(f);
  u += 0x7fffu + ((u >> 16) & 1u);   // RNE
  return (unsigned short)(u >> 16);
}
__device__ __forceinline__ float bf2f(unsigned short s) {
  return __uint_as_float(((unsigned)s) << 16);
}

// async global->LDS, 16B per lane, linear dest (wave-uniform base + lane*16)
__device__ __forceinline__ void gld_lds16(const void* g, void* l) {
  __builtin_amdgcn_global_load_lds(
      (const __attribute__((address_space(1))) void*)g,
      (__attribute__((address_space(3))) void*)l, 16, 0, 0);
}

#define BARM() do { __builtin_amdgcn_s_barrier(); asm volatile("" ::: "memory"); } while (0)
#define VMCNT(n) asm volatile("s_waitcnt vmcnt(" #n ")" ::: "memory")
// lgkmcnt(0) WITHOUT sched_barrier: certifies this wave's ds_reads complete
// before the following BARM (asm-asm ordering); MFMAs remain free to float.
#define LGKMW() asm volatile("s_waitcnt lgkmcnt(0)" ::: "memory")

// ---------------- pack W [K][N] f32 -> Wp fragment-linear bf16 (r6-proven) ----------------
// Wp element for (n,k): nt=n/16, kq=k/32, lane=(n%16)+((k%32)/8)*16, e=k%8
// -> Wp[((nt*KQ + kq)*64 + lane)*8 + e]. A wave's B-frag (16 rows x k32-slice)
// is ONE coalesced 1KB chunk: base + lane*16B.
__global__ void pack_w(const float* __restrict__ w, unsigned short* __restrict__ wp,
                       int K, int N) {
  __shared__ float tile[32][33];
  int nt32 = N >> 5;
  int bx = blockIdx.x % nt32;   // n 32-tile
  int by = blockIdx.x / nt32;   // k 32-tile == kq
  int tx = threadIdx.x & 31, ty = threadIdx.x >> 5;  // 32x8
#pragma unroll
  for (int r = 0; r < 32; r += 8)
    tile[ty + r][tx] = w[(size_t)(by * 32 + ty + r) * N + bx * 32 + tx];  // [k-loc][n-loc]
  __syncthreads();
  int KQ = K >> 5;
  int flat = threadIdx.x * 4;          // 1024 bf16 out per 32x32 tile
  int c = flat >> 9;                   // n-half -> nt = bx*2 + c
  int l = (flat >> 3) & 63;
  int e0 = flat & 7;                   // 0 or 4
  int nl = c * 16 + (l & 15);
  int kl = (l >> 4) * 8 + e0;
  unsigned short* o = wp + ((size_t)((bx * 2 + c) * KQ + by) * 64 + l) * 8 + e0;
#pragma unroll
  for (int e = 0; e < 4; ++e) o[e] = f2bf(tile[kl + e][nl]);
}

// ---------------- x f32 -> bf16 (chunk, zero-pad rows >= nvalid) ----------------
__global__ void cvt_x(const float* __restrict__ x, unsigned short* __restrict__ xb,
                      int rows, int nvalid, int D) {
  size_t total = (size_t)rows * D / 8;
  for (size_t i = (size_t)blockIdx.x * blockDim.x + threadIdx.x; i < total;
       i += (size_t)gridDim.x * blockDim.x) {
    size_t e = i * 8;
    int row = (int)(e / (size_t)D);
    uint4 ov;
    if (row < nvalid) {
      const float4* s = (const float4*)(x + e);
      float4 v0 = s[0], v1 = s[1];
      ov.x = (unsigned)f2bf(v0.x) | ((unsigned)f2bf(v0.y) << 16);
      ov.y = (unsigned)f2bf(v0.z) | ((unsigned)f2bf(v0.w) << 16);
      ov.z = (unsigned)f2bf(v1.x) | ((unsigned)f2bf(v1.y) << 16);
      ov.w = (unsigned)f2bf(v1.z) | ((unsigned)f2bf(v1.w) << 16);
    } else {
      ov.x = ov.y = ov.z = ov.w = 0u;
    }
    *(uint4*)(xb + e) = ov;
  }
}

// ---------------- 256x256 GEMM, 16 waves, A-only LDS, B from packed global ----------------
// Round-15 change vs r12 (best, 648us): remove B from LDS. Measured pipe
// demands per K64-tile/block in r12: LDS ~3600 cyc/CU vs MFMA ~2480 cyc/SIMD,
// wall 6400 = sum (serialized). B now streams from the L2-resident packed Wp
// straight to VGPRs (4 coalesced dwordx4 per K32 per wave, double-buffered in
// named reg sets, barrier-free) -> LDS demand drops to ~1800 < MFMA 2480,
// flipping the CU to MFMA-bound with room to hide all LDS under MFMA.
// LDS: 2 slots x A[2 khalf][256][32] bf16 = 64 KiB.
// VMCNT contract: per tile t VM issue order = [stage A(t+1)k1][B(t+1)k0 x4]
// [B(t+1)k1 x4][stage A(t+2)k0 LAST]; at end-of-tile, queue (oldest first) =
// A(t+1)k0 (from t-1), A(t+1)k1, B x8, A(t+2)k0 -> VMCNT(1) certifies tile
// t+1's A-stage + B-regs, keeps t+2's k0 stage in flight (T4: never 0).
// Race proof (as r12): stage into s^1 k1 gated by t-1's end barrier; stage
// into s k0 (half1) gated by mid barrier (k0 reads certified by LGKMW+BARM);
// B-loads are per-wave private registers, no cross-wave hazard.
__device__ __forceinline__ bf16x8 read_frag(const unsigned short* region, int row, int kel) {
  int ke = kel ^ (((row >> 1) & 3) << 3);
  return *(const bf16x8*)(region + row * 32 + ke);
}

__device__ __forceinline__ void stage_half(const unsigned short* gpanel, int K, int kofs,
                                           unsigned short* region, int tid) {
  int row = tid >> 2;                                  // 1024 threads -> 256 rows x 4
  int ke = ((tid & 3) * 8) ^ (((row >> 1) & 3) << 3);  // inverse-swizzled source
  gld_lds16(gpanel + (size_t)row * K + kofs + ke, region + tid * 8);
}

__device__ __forceinline__ void load_b4(const unsigned short* wpb, int KQ, int kq, int l,
                                        bf16x8* b) {
#pragma unroll
  for (int nn = 0; nn < 4; ++nn)
    b[nn] = *(const bf16x8*)(wpb + ((size_t)(nn * KQ + kq) * 64 + l) * 8);
}

// One K64 tile: slot SS (compile-time), BC = current 8 B-frags, BN = next.
#define TILE64(TT, SS, BC, BN)                                                  \
  do {                                                                          \
    const unsigned short* Ak0 = &lds[SS][0][0][0];                              \
    const unsigned short* Ak1 = &lds[SS][1][0][0];                              \
    unsigned short* nAk1 = &lds[(SS) ^ 1][1][0][0];                             \
    unsigned short* cAk0 = &lds[SS][0][0][0];                                   \
    bf16x8 av[4];                                                               \
    /* ---- half 0 (k0) ---- */                                                 \
    _Pragma("unroll") for (int mm = 0; mm < 4; ++mm)                            \
        av[mm] = read_frag(Ak0, wm * 64 + mm * 16 + lc, lk8);                   \
    if ((TT) + 1 < T) {                                                         \
      stage_half(Ap, K, ((TT) + 1) * 64 + 32, nAk1, tid);                       \
      load_b4(wpb, KQ, 2 * (TT) + 2, l, BN);          /* B(t+1) k0 */           \
    }                                                                           \
    _Pragma("unroll") for (int mm = 0; mm < 4; ++mm)                            \
        _Pragma("unroll") for (int nn = 0; nn < 4; ++nn)                        \
            acc[mm][nn] = __builtin_amdgcn_mfma_f32_16x16x32_bf16(              \
                av[mm], (BC)[nn], acc[mm][nn], 0, 0, 0);                        \
    LGKMW();                                                                    \
    BARM();   /* k0-region reads certified; gates half1's stage into s k0 */    \
    /* ---- half 1 (k1) ---- */                                                 \
    _Pragma("unroll") for (int mm = 0; mm < 4; ++mm)                            \
        av[mm] = read_frag(Ak1, wm * 64 + mm * 16 + lc, lk8);                   \
    if ((TT) + 1 < T) load_b4(wpb, KQ, 2 * (TT) + 3, l, (BN) + 4); /* k1 */     \
    if ((TT) + 2 < T) stage_half(Ap, K, ((TT) + 2) * 64, cAk0, tid); /* LAST */ \
    _Pragma("unroll") for (int mm = 0; mm < 4; ++mm)                            \
        _Pragma("unroll") for (int nn = 0; nn < 4; ++nn)                        \
            acc[mm][nn] = __builtin_amdgcn_mfma_f32_16x16x32_bf16(              \
                av[mm], (BC)[4 + nn], acc[mm][nn], 0, 0, 0);                    \
    LGKMW();                                                                    \
    if ((TT) + 2 < T) { VMCNT(1); } else { VMCNT(0); }                          \
    BARM();   /* tile t+1 (A-stage + B-regs) certified collectively */          \
  } while (0)

// Shared preamble+K-loop. Defines acc[4][4]; caller provides epilogue.
#define GEMM_PREAMBLE_AND_KLOOP()                                               \
  const int tid = threadIdx.x;                                                  \
  const int w = tid >> 6, l = tid & 63;                                         \
  const int wm = w >> 2, wn = w & 3;                                            \
  const int lc = l & 15, lk8 = (l >> 4) * 8;                                    \
  const int nbn = N >> 8;                                                       \
  const int nwg = gridDim.x;                                                    \
  const int q = nwg >> 3, rr = nwg & 7;                                         \
  const int xcd = blockIdx.x & 7, ib = blockIdx.x >> 3;                         \
  const int bswz = (xcd < rr ? xcd * (q + 1) : rr * (q + 1) + (xcd - rr) * q) + ib; \
  const int bm = bswz / nbn, bn = bswz - bm * nbn;                              \
  const unsigned short* Ap = A + (size_t)bm * 256 * K;                          \
  const int KQ = K >> 5;                                                        \
  const unsigned short* wpb = Wp + ((size_t)(bn * 16 + wn * 4) * KQ * 64) * 8;  \
  const int T = K >> 6;                                                         \
  f32x4 acc[4][4] = {};                                                         \
  bf16x8 bc[8], bn_[8];                                                         \
  stage_half(Ap, K, 0, &lds[0][0][0][0], tid);                                  \
  stage_half(Ap, K, 32, &lds[0][1][0][0], tid);                                 \
  load_b4(wpb, KQ, 0, l, bc);                                                   \
  load_b4(wpb, KQ, 1, l, bc + 4);                                               \
  if (T > 1) stage_half(Ap, K, 64, &lds[1][0][0][0], tid);  /* t1 k0 LAST */    \
  if (T > 1) { VMCNT(1); } else { VMCNT(0); }                                   \
  BARM();                                                                       \
  for (int t = 0; t < T; t += 2) {                                              \
    TILE64(t, 0, bc, bn_);                                                      \
    if (t + 1 < T) TILE64(t + 1, 1, bn_, bc);                                   \
  }

__global__ __launch_bounds__(1024, 1) void gemm256(
    const unsigned short* __restrict__ A,   // [M][K] bf16
    const unsigned short* __restrict__ Wp,  // packed [N/16][K/32][64][8] bf16
    const float* __restrict__ bias,         // [N] f32
    unsigned short* __restrict__ C,         // [M][N] bf16
    int N, int K) {
  __shared__ alignas(16) unsigned short lds[2][2][256][32];   // 64 KiB (A only)
  GEMM_PREAMBLE_AND_KLOOP();

  // ---- epilogue: acc -> LDS (row-XOR swizzle) -> coalesced dwordx4 stores ----
  unsigned short* eps = &lds[0][0][0][0];   // [128][256] bf16 = all 64 KiB
  float bv[4];
#pragma unroll
  for (int nn = 0; nn < 4; ++nn) bv[nn] = bias[bn * 256 + wn * 64 + nn * 16 + lc];

#pragma unroll
  for (int r = 0; r < 2; ++r) {
    if ((wm >> 1) == r) {                      // waves wm=2r,2r+1 own rows r*128..+127
#pragma unroll
      for (int mm = 0; mm < 4; ++mm) {
#pragma unroll
        for (int nn = 0; nn < 4; ++nn) {
          int lcol = wn * 64 + nn * 16 + lc;
#pragma unroll
          for (int j = 0; j < 4; ++j) {
            int lrow = (wm & 1) * 64 + mm * 16 + (l >> 4) * 4 + j;
            float v = fmaxf(acc[mm][nn][j] + bv[nn], 0.0f);
            eps[lrow * 256 + (lcol ^ (((lrow >> 2) & 3) << 4))] = f2bf(v);
          }
        }
      }
    }
    BARM();
#pragma unroll
    for (int it = 0; it < 4; ++it) {
      int flat = it * 1024 + tid;          // 4096 = 128 rows x 32 col-granules
      int lrow = flat >> 5, cb = flat & 31;
      int ce = (cb * 8) ^ (((lrow >> 2) & 3) << 4);
      uint4 v = *(const uint4*)&eps[lrow * 256 + ce];
      *(uint4*)&C[(size_t)(bm * 256 + r * 128 + lrow) * N + bn * 256 + cb * 8] = v;
    }
    BARM();
  }
}

// Last layer: identical K-loop; segment-sum relu'd outputs per graph via
// atomicAdd into part[G][N] (batch sorted; pad rows -> sentinel -1).
__global__ __launch_bounds__(1024, 1) void gemm_pool(
    const unsigned short* __restrict__ A,   // [M][K] bf16 (chunk base)
    const unsigned short* __restrict__ Wp,  // packed [N/16][K/32][64][8] bf16
    const float* __restrict__ bias,         // [N] f32
    const int* __restrict__ batch,          // [Nn] sorted graph ids (global)
    float* __restrict__ part,               // [G][N] f32 accumulators
    int N, int K, int row0, int Nn) {       // row0 = chunk offset in global rows
  __shared__ alignas(16) unsigned short lds[2][2][256][32];   // 64 KiB (A only)
  __shared__ int batchLS[256];
  GEMM_PREAMBLE_AND_KLOOP();

  unsigned short* eps = &lds[0][0][0][0];
  if (tid < 256) {
    int grow = row0 + bm * 256 + tid;
    batchLS[tid] = (grow < Nn) ? batch[grow] : -1;
  }
  float bv[4];
#pragma unroll
  for (int nn = 0; nn < 4; ++nn) bv[nn] = bias[bn * 256 + wn * 64 + nn * 16 + lc];

#pragma unroll
  for (int r = 0; r < 2; ++r) {
    if ((wm >> 1) == r) {
#pragma unroll
      for (int mm = 0; mm < 4; ++mm) {
#pragma unroll
        for (int nn = 0; nn < 4; ++nn) {
          int lcol = wn * 64 + nn * 16 + lc;
#pragma unroll
          for (int j = 0; j < 4; ++j) {
            int lrow = (wm & 1) * 64 + mm * 16 + (l >> 4) * 4 + j;
            float v = fmaxf(acc[mm][nn][j] + bv[nn], 0.0f);
            eps[lrow * 256 + (lcol ^ (((lrow >> 2) & 3) << 4))] = f2bf(v);
          }
        }
      }
    }
    BARM();
    // column scan: thread -> (col = tid&255, rows qt*32..qt*32+31)
    {
      int col = tid & 255;
      int qt = tid >> 8;                   // 0..3
      int gcur = -2;
      float run = 0.f;
      int gcolbase = bn * 256 + col;
      for (int i = 0; i < 32; ++i) {
        int lr = qt * 32 + i;
        int g = batchLS[r * 128 + lr];
        if (g != gcur) {
          if (gcur >= 0) atomicAdd(&part[(size_t)gcur * N + gcolbase], run);
          gcur = g; run = 0.f;
        }
        run += bf2f(eps[lr * 256 + (col ^ (((lr >> 2) & 3) << 4))]);
      }
      if (gcur >= 0) atomicAdd(&part[(size_t)gcur * N + gcolbase], run);
    }
    BARM();
  }
}

// ---------------- pool finalize ----------------
__global__ void zero_part(float* __restrict__ part, int n) {
  int i = blockIdx.x * blockDim.x + threadIdx.x;
  if (i < n) part[i] = 0.f;
}

__global__ void pool_div(const float* __restrict__ part, const int* __restrict__ batch,
                         float* __restrict__ out, int n, int D, int G) {
  int idx = blockIdx.x * blockDim.x + threadIdx.x;
  if (idx >= G * D) return;
  int g = idx / D;
  int lo, hi;
  { int a = 0, b = n; while (a < b) { int m = (a + b) >> 1; if (batch[m] < g) a = m + 1; else b = m; } lo = a; }
  { int a = lo, b = n; while (a < b) { int m = (a + b) >> 1; if (batch[m] < g + 1) a = m + 1; else b = m; } hi = a; }
  out[idx] = part[idx] / (float)(hi - lo);
}

// ---------------- launcher ----------------
static inline size_t align256(size_t x) { return (x + 255) & ~(size_t)255; }

extern "C" void kernel_launch(void* const* d_in, const int* in_sizes, int n_in,
                              void* d_out, int out_size, void* d_ws, size_t ws_size,
                              hipStream_t stream) {
  const float* x = (const float*)d_in[0];
  // d_in[1] = edge_index (unused by the math)
  const int* batch = (const int*)d_in[2];
  const float* W0 = (const float*)d_in[3];
  const float* b0 = (const float*)d_in[4];
  const float* W1 = (const float*)d_in[5];
  const float* b1 = (const float*)d_in[6];
  const float* W2 = (const float*)d_in[7];
  const float* b2 = (const float*)d_in[8];
  float* out = (float*)d_out;

  const int Nn = in_sizes[2];                 // 100000 nodes
  const int DIN = 512, DH = 1024, DOUT = 512;
  const int G = out_size / DOUT;              // 128
  const int Mpad = ((Nn + 255) / 256) * 256;  // 100096

  // workspace layout
  uint8_t* p = (uint8_t*)d_ws;
  unsigned short* W0p = (unsigned short*)p; p += align256((size_t)DH * DIN * 2);
  unsigned short* W1p = (unsigned short*)p; p += align256((size_t)DH * DH * 2);
  unsigned short* W2p = (unsigned short*)p; p += align256((size_t)DOUT * DH * 2);
  float* part         = (float*)p;          p += align256((size_t)G * DOUT * 4);
  size_t used = (size_t)(p - (uint8_t*)d_ws);
  size_t avail = ws_size > used ? ws_size - used : 0;
  size_t per_row = (size_t)(DIN + DH + DH) * 2;       // xb + h0 + h1 bytes per row
  long long chl = (long long)(avail / per_row);
  chl = (chl / 256) * 256;
  int CH = (int)(chl < 256 ? 256 : chl);
  if (CH > Mpad) CH = Mpad;
  unsigned short* xb = (unsigned short*)p; p += align256((size_t)CH * DIN * 2);
  unsigned short* h0 = (unsigned short*)p; p += align256((size_t)CH * DH * 2);
  unsigned short* h1 = (unsigned short*)p; p += align256((size_t)CH * DH * 2);

  // 0) zero the pooling accumulators
  zero_part<<<dim3((G * DOUT + 255) / 256), 256, 0, stream>>>(part, G * DOUT);

  // 1) weights: pack + convert to fragment-linear bf16
  pack_w<<<dim3((DH / 32) * (DIN / 32)), 256, 0, stream>>>(W0, W0p, DIN, DH);
  pack_w<<<dim3((DH / 32) * (DH / 32)), 256, 0, stream>>>(W1, W1p, DH, DH);
  pack_w<<<dim3((DOUT / 32) * (DH / 32)), 256, 0, stream>>>(W2, W2p, DH, DOUT);

  // 2) chunked 3-layer MLP (single chunk when ws allows); L2 fuses the pool
  for (int off = 0; off < Mpad; off += CH) {
    int rows = Mpad - off; if (rows > CH) rows = CH;
    int nvalid = Nn - off;
    size_t cvt_threads = (size_t)rows * DIN / 8;
    int cvt_blocks = (int)((cvt_threads + 255) / 256);
    if (cvt_blocks > 2048) cvt_blocks = 2048;
    cvt_x<<<dim3(cvt_blocks), 256, 0, stream>>>(x + (size_t)off * DIN, xb, rows, nvalid, DIN);

    gemm256<<<dim3((rows / 256) * (DH / 256)), 1024, 0, stream>>>(xb, W0p, b0, h0, DH, DIN);
    gemm256<<<dim3((rows / 256) * (DH / 256)), 1024, 0, stream>>>(h0, W1p, b1, h1, DH, DH);
    gemm_pool<<<dim3((rows / 256) * (DOUT / 256)), 1024, 0, stream>>>(
        h1, W2p, b2, batch, part, DOUT, DH, off, Nn);
  }

  // 3) finalize: mean = sum / count
  pool_div<<<dim3((G * DOUT + 255) / 256), 256, 0, stream>>>(part, batch, out, Nn, DOUT, G);
}

// Round 16
// 646.957 us; speedup vs baseline: 5.3209x; 5.3209x over previous
//
#include <hip/hip_runtime.h>
#include <cstdint>
#include <cstddef>

// ---------------- types / helpers ----------------
typedef __bf16 bf16x8 __attribute__((ext_vector_type(8)));
typedef float f32x4 __attribute__((ext_vector_type(4)));

__device__ __forceinline__ unsigned short f2bf(float f) {
  unsigned u = __float_as_uint(f);
  u += 0x7fffu + ((u >> 16) & 1u);   // RNE
  return (unsigned short)(u >> 16);
}
__device__ __forceinline__ float bf2f(unsigned short s) {
  return __uint_as_float(((unsigned)s) << 16);
}

// async global->LDS, 16B per lane, linear dest (wave-uniform base + lane*16)
__device__ __forceinline__ void gld_lds16(const void* g, void* l) {
  __builtin_amdgcn_global_load_lds(
      (const __attribute__((address_space(1))) void*)g,
      (__attribute__((address_space(3))) void*)l, 16, 0, 0);
}

#define BARM() do { __builtin_amdgcn_s_barrier(); asm volatile("" ::: "memory"); } while (0)
#define VMCNT(n) asm volatile("s_waitcnt vmcnt(" #n ")" ::: "memory")
// lgkmcnt(0) WITHOUT sched_barrier: certifies this wave's ds_reads complete
// before the following BARM (asm-asm ordering); MFMAs remain free to float.
#define LGKMW() asm volatile("s_waitcnt lgkmcnt(0)" ::: "memory")

// ---------------- transpose + convert W [K][N] f32 -> Wt [N][K] bf16 ----------------
__global__ void transpose_w(const float* __restrict__ w, unsigned short* __restrict__ wt,
                            int K, int N) {
  __shared__ float tile[32][33];
  int nt = N >> 5;
  int bx = blockIdx.x % nt;   // n tile
  int by = blockIdx.x / nt;   // k tile
  int tx = threadIdx.x & 31, ty = threadIdx.x >> 5;  // 32x8
#pragma unroll
  for (int r = 0; r < 32; r += 8)
    tile[ty + r][tx] = w[(size_t)(by * 32 + ty + r) * N + bx * 32 + tx];
  __syncthreads();
#pragma unroll
  for (int r = 0; r < 32; r += 8)
    wt[(size_t)(bx * 32 + ty + r) * K + by * 32 + tx] = f2bf(tile[tx][ty + r]);
}

// ---------------- x f32 -> bf16 (chunk, zero-pad rows >= nvalid) ----------------
__global__ void cvt_x(const float* __restrict__ x, unsigned short* __restrict__ xb,
                      int rows, int nvalid, int D) {
  size_t total = (size_t)rows * D / 8;
  for (size_t i = (size_t)blockIdx.x * blockDim.x + threadIdx.x; i < total;
       i += (size_t)gridDim.x * blockDim.x) {
    size_t e = i * 8;
    int row = (int)(e / (size_t)D);
    uint4 ov;
    if (row < nvalid) {
      const float4* s = (const float4*)(x + e);
      float4 v0 = s[0], v1 = s[1];
      ov.x = (unsigned)f2bf(v0.x) | ((unsigned)f2bf(v0.y) << 16);
      ov.y = (unsigned)f2bf(v0.z) | ((unsigned)f2bf(v0.w) << 16);
      ov.z = (unsigned)f2bf(v1.x) | ((unsigned)f2bf(v1.y) << 16);
      ov.w = (unsigned)f2bf(v1.z) | ((unsigned)f2bf(v1.w) << 16);
    } else {
      ov.x = ov.y = ov.z = ov.w = 0u;
    }
    *(uint4*)(xb + e) = ov;
  }
}

// ---------------- 256x256 GEMM, 16 waves, 2-barrier/K64 relaxed schedule ----------------
// FINAL (r12 verbatim — verified best, 648us total; r15's B-in-regs at 16
// waves spilled: 4 waves/SIMD caps VGPR at 128, acc64+B64+av32 doesn't fit).
// Per tile t (slot s=t&1): half0 {reads k0; stage(t+1)k1->s^1; 16 MFMA;
// LGKMW; BAR} half1 {reads k1; stage(t+2)k0->s; 16 MFMA; LGKMW; VMCNT(2);
// BAR}. Race proof:
//  (1) staged-data-ready: per-wave VMCNT(2) at tile t retires the 4 oldest
//      gld_lds = tile t+1 k0 (issued t-1, 2nd half) + k1 (issued t, 1st half);
//      the following BAR makes certification collective before t+1's reads.
//  (2) no overwrite of live reads: writes into slot-s k0 (stage at t's 2nd
//      half) issue only after the mid-tile BAR, which every wave reaches only
//      after its LGKMW certified its k0 ds_reads complete. Same for k1 via the
//      end-of-tile BAR gating t+1's 1st-half stage into slot-s k1.
//  (3) gld_lds/ds_read are memory ops: cannot cross BARM's memory clobber.
__device__ __forceinline__ bf16x8 read_frag(const unsigned short* region, int row, int kel) {
  int ke = kel ^ (((row >> 1) & 3) << 3);
  return *(const bf16x8*)(region + row * 32 + ke);
}

__device__ __forceinline__ void stage_half(const unsigned short* gpanel, int K, int kofs,
                                           unsigned short* region, int tid) {
  int row = tid >> 2;                                  // 1024 threads -> 256 rows x 4
  int ke = ((tid & 3) * 8) ^ (((row >> 1) & 3) << 3);  // inverse-swizzled source
  gld_lds16(gpanel + (size_t)row * K + kofs + ke, region + tid * 8);
}

#define MFMA16X(BV)                                                             \
  _Pragma("unroll") for (int mm = 0; mm < 4; ++mm)                              \
      _Pragma("unroll") for (int nn = 0; nn < 4; ++nn)                          \
          acc[mm][nn] = __builtin_amdgcn_mfma_f32_16x16x32_bf16(                \
              av[mm], BV[nn], acc[mm][nn], 0, 0, 0)

// Shared K-loop body. Defines acc[4][4]; caller provides epilogue.
#define GEMM_PREAMBLE_AND_KLOOP()                                               \
  const int tid = threadIdx.x;                                                  \
  const int w = tid >> 6, l = tid & 63;                                         \
  const int wm = w >> 2, wn = w & 3;                                            \
  const int lc = l & 15, lk8 = (l >> 4) * 8;                                    \
  const int nbn = N >> 8;                                                       \
  const int nwg = gridDim.x;                                                    \
  const int q = nwg >> 3, rr = nwg & 7;                                         \
  const int xcd = blockIdx.x & 7, ib = blockIdx.x >> 3;                         \
  const int bswz = (xcd < rr ? xcd * (q + 1) : rr * (q + 1) + (xcd - rr) * q) + ib; \
  const int bm = bswz / nbn, bn = bswz - bm * nbn;                              \
  const unsigned short* Ap = A + (size_t)bm * 256 * K;                          \
  const unsigned short* Bp = Bt + (size_t)bn * 256 * K;                         \
  const int T = K >> 6;                                                         \
  f32x4 acc[4][4] = {};                                                         \
  stage_half(Ap, K, 0, &lds[0][0][0][0][0], tid);                               \
  stage_half(Bp, K, 0, &lds[0][1][0][0][0], tid);                               \
  stage_half(Ap, K, 32, &lds[0][0][1][0][0], tid);                              \
  stage_half(Bp, K, 32, &lds[0][1][1][0][0], tid);                              \
  stage_half(Ap, K, 64, &lds[1][0][0][0][0], tid);                              \
  stage_half(Bp, K, 64, &lds[1][1][0][0][0], tid);                              \
  VMCNT(2);                                                                     \
  BARM();                                                                       \
  for (int t = 0; t < T; ++t) {                                                 \
    const int s = t & 1;                                                        \
    const unsigned short* Ak0 = &lds[s][0][0][0][0];                            \
    const unsigned short* Ak1 = &lds[s][0][1][0][0];                            \
    const unsigned short* Bk0 = &lds[s][1][0][0][0];                            \
    const unsigned short* Bk1 = &lds[s][1][1][0][0];                            \
    unsigned short* nAk1 = &lds[s ^ 1][0][1][0][0];                             \
    unsigned short* nBk1 = &lds[s ^ 1][1][1][0][0];                             \
    unsigned short* cAk0 = &lds[s][0][0][0][0];                                 \
    unsigned short* cBk0 = &lds[s][1][0][0][0];                                 \
    bf16x8 av[4], bq[4];                                                        \
    /* ---- half 0 (k0) ---- */                                                 \
    _Pragma("unroll") for (int mm = 0; mm < 4; ++mm)                            \
        av[mm] = read_frag(Ak0, wm * 64 + mm * 16 + lc, lk8);                   \
    _Pragma("unroll") for (int nn = 0; nn < 4; ++nn)                            \
        bq[nn] = read_frag(Bk0, wn * 64 + nn * 16 + lc, lk8);                   \
    if (t + 1 < T) {                                                            \
      stage_half(Ap, K, (t + 1) * 64 + 32, nAk1, tid);                          \
      stage_half(Bp, K, (t + 1) * 64 + 32, nBk1, tid);                          \
    }                                                                           \
    MFMA16X(bq);                                                                \
    LGKMW();                                                                    \
    BARM();   /* k0-region reads certified; gates the stage below */            \
    /* ---- half 1 (k1) ---- */                                                 \
    _Pragma("unroll") for (int mm = 0; mm < 4; ++mm)                            \
        av[mm] = read_frag(Ak1, wm * 64 + mm * 16 + lc, lk8);                   \
    _Pragma("unroll") for (int nn = 0; nn < 4; ++nn)                            \
        bq[nn] = read_frag(Bk1, wn * 64 + nn * 16 + lc, lk8);                   \
    if (t + 2 < T) {                                                            \
      stage_half(Ap, K, (t + 2) * 64, cAk0, tid);                               \
      stage_half(Bp, K, (t + 2) * 64, cBk0, tid);                               \
    }                                                                           \
    MFMA16X(bq);                                                                \
    LGKMW();                                                                    \
    if (t + 2 < T) { VMCNT(2); } else { VMCNT(0); }                             \
    BARM();   /* tile t+1 certified collectively; k1 reads certified */         \
  }

__global__ __launch_bounds__(1024, 1) void gemm256(
    const unsigned short* __restrict__ A,   // [M][K] bf16
    const unsigned short* __restrict__ Bt,  // [N][K] bf16
    const float* __restrict__ bias,         // [N] f32
    unsigned short* __restrict__ C,         // [M][N] bf16
    int N, int K) {
  __shared__ alignas(16) unsigned short lds[2][2][2][256][32];   // 128 KiB
  GEMM_PREAMBLE_AND_KLOOP();

  // ---- epilogue: acc -> LDS (row-XOR swizzle) -> coalesced dwordx4 stores ----
  unsigned short* eps = &lds[0][0][0][0][0];   // [128][256] bf16 per round
  float bv[4];
#pragma unroll
  for (int nn = 0; nn < 4; ++nn) bv[nn] = bias[bn * 256 + wn * 64 + nn * 16 + lc];

#pragma unroll
  for (int r = 0; r < 2; ++r) {
    if ((wm >> 1) == r) {                      // waves wm=2r,2r+1 own rows r*128..+127
#pragma unroll
      for (int mm = 0; mm < 4; ++mm) {
#pragma unroll
        for (int nn = 0; nn < 4; ++nn) {
          int lcol = wn * 64 + nn * 16 + lc;
#pragma unroll
          for (int j = 0; j < 4; ++j) {
            int lrow = (wm & 1) * 64 + mm * 16 + (l >> 4) * 4 + j;
            float v = fmaxf(acc[mm][nn][j] + bv[nn], 0.0f);
            eps[lrow * 256 + (lcol ^ (((lrow >> 2) & 3) << 4))] = f2bf(v);
          }
        }
      }
    }
    BARM();
#pragma unroll
    for (int it = 0; it < 4; ++it) {
      int flat = it * 1024 + tid;          // 4096 = 128 rows x 32 col-granules
      int lrow = flat >> 5, cb = flat & 31;
      int ce = (cb * 8) ^ (((lrow >> 2) & 3) << 4);
      uint4 v = *(const uint4*)&eps[lrow * 256 + ce];
      *(uint4*)&C[(size_t)(bm * 256 + r * 128 + lrow) * N + bn * 256 + cb * 8] = v;
    }
    BARM();
  }
}

// Last layer: identical K-loop; segment-sum relu'd outputs per graph via
// atomicAdd into part[G][N] (batch sorted; pad rows -> sentinel -1).
__global__ __launch_bounds__(1024, 1) void gemm_pool(
    const unsigned short* __restrict__ A,   // [M][K] bf16 (chunk base)
    const unsigned short* __restrict__ Bt,  // [N][K] bf16
    const float* __restrict__ bias,         // [N] f32
    const int* __restrict__ batch,          // [Nn] sorted graph ids (global)
    float* __restrict__ part,               // [G][N] f32 accumulators
    int N, int K, int row0, int Nn) {       // row0 = chunk offset in global rows
  __shared__ alignas(16) unsigned short lds[2][2][2][256][32];   // 128 KiB
  GEMM_PREAMBLE_AND_KLOOP();

  unsigned short* eps = &lds[0][0][0][0][0];
  int* batchLS = (int*)&lds[1][0][0][0][0];   // slot 1 is free post-loop
  if (tid < 256) {
    int grow = row0 + bm * 256 + tid;
    batchLS[tid] = (grow < Nn) ? batch[grow] : -1;
  }
  float bv[4];
#pragma unroll
  for (int nn = 0; nn < 4; ++nn) bv[nn] = bias[bn * 256 + wn * 64 + nn * 16 + lc];

#pragma unroll
  for (int r = 0; r < 2; ++r) {
    if ((wm >> 1) == r) {
#pragma unroll
      for (int mm = 0; mm < 4; ++mm) {
#pragma unroll
        for (int nn = 0; nn < 4; ++nn) {
          int lcol = wn * 64 + nn * 16 + lc;
#pragma unroll
          for (int j = 0; j < 4; ++j) {
            int lrow = (wm & 1) * 64 + mm * 16 + (l >> 4) * 4 + j;
            float v = fmaxf(acc[mm][nn][j] + bv[nn], 0.0f);
            eps[lrow * 256 + (lcol ^ (((lrow >> 2) & 3) << 4))] = f2bf(v);
          }
        }
      }
    }
    BARM();
    // column scan: thread -> (col = tid&255, rows qt*32..qt*32+31)
    {
      int col = tid & 255;
      int qt = tid >> 8;                   // 0..3
      int gcur = -2;
      float run = 0.f;
      int gcolbase = bn * 256 + col;
      for (int i = 0; i < 32; ++i) {
        int lr = qt * 32 + i;
        int g = batchLS[r * 128 + lr];
        if (g != gcur) {
          if (gcur >= 0) atomicAdd(&part[(size_t)gcur * N + gcolbase], run);
          gcur = g; run = 0.f;
        }
        run += bf2f(eps[lr * 256 + (col ^ (((lr >> 2) & 3) << 4))]);
      }
      if (gcur >= 0) atomicAdd(&part[(size_t)gcur * N + gcolbase], run);
    }
    BARM();
  }
}

// ---------------- pool finalize ----------------
__global__ void zero_part(float* __restrict__ part, int n) {
  int i = blockIdx.x * blockDim.x + threadIdx.x;
  if (i < n) part[i] = 0.f;
}

__global__ void pool_div(const float* __restrict__ part, const int* __restrict__ batch,
                         float* __restrict__ out, int n, int D, int G) {
  int idx = blockIdx.x * blockDim.x + threadIdx.x;
  if (idx >= G * D) return;
  int g = idx / D;
  int lo, hi;
  { int a = 0, b = n; while (a < b) { int m = (a + b) >> 1; if (batch[m] < g) a = m + 1; else b = m; } lo = a; }
  { int a = lo, b = n; while (a < b) { int m = (a + b) >> 1; if (batch[m] < g + 1) a = m + 1; else b = m; } hi = a; }
  out[idx] = part[idx] / (float)(hi - lo);
}

// ---------------- launcher ----------------
static inline size_t align256(size_t x) { return (x + 255) & ~(size_t)255; }

extern "C" void kernel_launch(void* const* d_in, const int* in_sizes, int n_in,
                              void* d_out, int out_size, void* d_ws, size_t ws_size,
                              hipStream_t stream) {
  const float* x = (const float*)d_in[0];
  // d_in[1] = edge_index (unused by the math)
  const int* batch = (const int*)d_in[2];
  const float* W0 = (const float*)d_in[3];
  const float* b0 = (const float*)d_in[4];
  const float* W1 = (const float*)d_in[5];
  const float* b1 = (const float*)d_in[6];
  const float* W2 = (const float*)d_in[7];
  const float* b2 = (const float*)d_in[8];
  float* out = (float*)d_out;

  const int Nn = in_sizes[2];                 // 100000 nodes
  const int DIN = 512, DH = 1024, DOUT = 512;
  const int G = out_size / DOUT;              // 128
  const int Mpad = ((Nn + 255) / 256) * 256;  // 100096

  // workspace layout (h2 eliminated)
  uint8_t* p = (uint8_t*)d_ws;
  unsigned short* W0t = (unsigned short*)p; p += align256((size_t)DH * DIN * 2);
  unsigned short* W1t = (unsigned short*)p; p += align256((size_t)DH * DH * 2);
  unsigned short* W2t = (unsigned short*)p; p += align256((size_t)DOUT * DH * 2);
  float* part         = (float*)p;          p += align256((size_t)G * DOUT * 4);
  size_t used = (size_t)(p - (uint8_t*)d_ws);
  size_t avail = ws_size > used ? ws_size - used : 0;
  size_t per_row = (size_t)(DIN + DH + DH) * 2;       // xb + h0 + h1 bytes per row
  long long chl = (long long)(avail / per_row);
  chl = (chl / 256) * 256;
  int CH = (int)(chl < 256 ? 256 : chl);
  if (CH > Mpad) CH = Mpad;
  unsigned short* xb = (unsigned short*)p; p += align256((size_t)CH * DIN * 2);
  unsigned short* h0 = (unsigned short*)p; p += align256((size_t)CH * DH * 2);
  unsigned short* h1 = (unsigned short*)p; p += align256((size_t)CH * DH * 2);

  // 0) zero the pooling accumulators
  zero_part<<<dim3((G * DOUT + 255) / 256), 256, 0, stream>>>(part, G * DOUT);

  // 1) weights: transpose + convert to bf16 [N][K]
  transpose_w<<<dim3((DIN / 32) * (DH / 32)), 256, 0, stream>>>(W0, W0t, DIN, DH);
  transpose_w<<<dim3((DH / 32) * (DH / 32)), 256, 0, stream>>>(W1, W1t, DH, DH);
  transpose_w<<<dim3((DH / 32) * (DOUT / 32)), 256, 0, stream>>>(W2, W2t, DH, DOUT);

  // 2) chunked 3-layer MLP (single chunk when ws allows); L2 fuses the pool
  for (int off = 0; off < Mpad; off += CH) {
    int rows = Mpad - off; if (rows > CH) rows = CH;
    int nvalid = Nn - off;
    size_t cvt_threads = (size_t)rows * DIN / 8;
    int cvt_blocks = (int)((cvt_threads + 255) / 256);
    if (cvt_blocks > 2048) cvt_blocks = 2048;
    cvt_x<<<dim3(cvt_blocks), 256, 0, stream>>>(x + (size_t)off * DIN, xb, rows, nvalid, DIN);

    gemm256<<<dim3((rows / 256) * (DH / 256)), 1024, 0, stream>>>(xb, W0t, b0, h0, DH, DIN);
    gemm256<<<dim3((rows / 256) * (DH / 256)), 1024, 0, stream>>>(h0, W1t, b1, h1, DH, DH);
    gemm_pool<<<dim3((rows / 256) * (DOUT / 256)), 1024, 0, stream>>>(
        h1, W2t, b2, batch, part, DOUT, DH, off, Nn);
  }

  // 3) finalize: mean = sum / count
  pool_div<<<dim3((G * DOUT + 255) / 256), 256, 0, stream>>>(part, batch, out, Nn, DOUT, G);
}

// Round 17
// 614.406 us; speedup vs baseline: 5.6028x; 1.0530x over previous
//
#include <hip/hip_runtime.h>
#include <cstdint>
#include <cstddef>

// ---------------- types / helpers ----------------
typedef __bf16 bf16x8 __attribute__((ext_vector_type(8)));
typedef float f32x4 __attribute__((ext_vector_type(4)));

__device__ __forceinline__ unsigned short f2bf(float f) {
  unsigned u = __float_as_uint(f);
  u += 0x7fffu + ((u >> 16) & 1u);   // RNE
  return (unsigned short)(u >> 16);
}
__device__ __forceinline__ float bf2f(unsigned short s) {
  return __uint_as_float(((unsigned)s) << 16);
}

// async global->LDS, 16B per lane, linear dest (wave-uniform base + lane*16)
__device__ __forceinline__ void gld_lds16(const void* g, void* l) {
  __builtin_amdgcn_global_load_lds(
      (const __attribute__((address_space(1))) void*)g,
      (__attribute__((address_space(3))) void*)l, 16, 0, 0);
}

#define BARM() do { __builtin_amdgcn_s_barrier(); asm volatile("" ::: "memory"); } while (0)
#define VMCNT(n) asm volatile("s_waitcnt vmcnt(" #n ")" ::: "memory")
// lgkmcnt(0) WITHOUT sched_barrier: certifies this wave's ds_reads complete
// before the following BARM (asm-asm ordering); MFMAs remain free to float.
#define LGKMW() asm volatile("s_waitcnt lgkmcnt(0)" ::: "memory")

// ---------------- transpose + convert W [K][N] f32 -> Wt [N][K] bf16 ----------------
__global__ void transpose_w(const float* __restrict__ w, unsigned short* __restrict__ wt,
                            int K, int N) {
  __shared__ float tile[32][33];
  int nt = N >> 5;
  int bx = blockIdx.x % nt;   // n tile
  int by = blockIdx.x / nt;   // k tile
  int tx = threadIdx.x & 31, ty = threadIdx.x >> 5;  // 32x8
#pragma unroll
  for (int r = 0; r < 32; r += 8)
    tile[ty + r][tx] = w[(size_t)(by * 32 + ty + r) * N + bx * 32 + tx];
  __syncthreads();
#pragma unroll
  for (int r = 0; r < 32; r += 8)
    wt[(size_t)(bx * 32 + ty + r) * K + by * 32 + tx] = f2bf(tile[tx][ty + r]);
}

// ---------------- x f32 -> bf16 (chunk, zero-pad rows >= nvalid) ----------------
__global__ void cvt_x(const float* __restrict__ x, unsigned short* __restrict__ xb,
                      int rows, int nvalid, int D) {
  size_t total = (size_t)rows * D / 8;
  for (size_t i = (size_t)blockIdx.x * blockDim.x + threadIdx.x; i < total;
       i += (size_t)gridDim.x * blockDim.x) {
    size_t e = i * 8;
    int row = (int)(e / (size_t)D);
    uint4 ov;
    if (row < nvalid) {
      const float4* s = (const float4*)(x + e);
      float4 v0 = s[0], v1 = s[1];
      ov.x = (unsigned)f2bf(v0.x) | ((unsigned)f2bf(v0.y) << 16);
      ov.y = (unsigned)f2bf(v0.z) | ((unsigned)f2bf(v0.w) << 16);
      ov.z = (unsigned)f2bf(v1.x) | ((unsigned)f2bf(v1.y) << 16);
      ov.w = (unsigned)f2bf(v1.z) | ((unsigned)f2bf(v1.w) << 16);
    } else {
      ov.x = ov.y = ov.z = ov.w = 0u;
    }
    *(uint4*)(xb + e) = ov;
  }
}

// ---------------- 256x128 GEMM, 8 waves, 2 blocks/CU, 3-slot ring ----------------
// Round-17 change vs r12 (best, 647us): split the CU's 16 waves into TWO
// independent barrier domains (2 co-resident 8-wave blocks). r12's wall =
// LDS(3600) + MFMA(2480) serialized by the single block-wide rendezvous;
// independent domains let block A's MFMA phase cover block B's LDS phase.
// (r5's failed 2-block attempt had only 2 waves/SIMD; this keeps 4/SIMD.)
// Resources checked FIRST (r3/r15 lesson): acc64+frags32+addr ~116 < 128
// VGPR cap at (512,4); LDS 3 x 24KB = 73.7KB -> 2 blocks = 147KB <= 160.
// Tile 256x128, BK=32, waves 4Mx2N (per-wave 64x64, r12 fragment pattern).
// 3-slot ring: tile t reads slot t%3; stages tile t+2 into slot (t-1)%3 —
// never the slot being read -> NO mid-tile barrier. One VMCNT(3)+BAR per
// K32 tile; staged data waited a full tile after issue (never fresh).
// Race proof: stage target slot (t-1)%3 was last read at tile t-1, whose
// readers passed LGKMW before t-1's BAR; stage is issued after that BAR
// (memory ops can't cross BARM). VMCNT(3) at tile t retires the 3 oldest
// glds = tile t+1's stages (issued at t-1), keeps t+2's 3 in flight.
__device__ __forceinline__ bf16x8 read_frag(const unsigned short* region, int row, int kel) {
  int ke = kel ^ (((row >> 1) & 3) << 3);
  return *(const bf16x8*)(region + row * 32 + ke);
}

// A tile [256][32]: 2 glds/thread (512 threads). B tile [128][32]: 1 gld.
__device__ __forceinline__ void stage_a(const unsigned short* gp, int K, int kofs,
                                        unsigned short* region, int tid) {
#pragma unroll
  for (int r = 0; r < 2; ++r) {
    int row = r * 128 + (tid >> 2);
    int ke = ((tid & 3) * 8) ^ (((row >> 1) & 3) << 3);  // inverse-swizzled source
    gld_lds16(gp + (size_t)row * K + kofs + ke, region + r * 4096 + tid * 8);
  }
}
__device__ __forceinline__ void stage_b(const unsigned short* gp, int K, int kofs,
                                        unsigned short* region, int tid) {
  int row = tid >> 2;
  int ke = ((tid & 3) * 8) ^ (((row >> 1) & 3) << 3);
  gld_lds16(gp + (size_t)row * K + kofs + ke, region + tid * 8);
}

#define MFMA16X(BV)                                                             \
  _Pragma("unroll") for (int mm = 0; mm < 4; ++mm)                              \
      _Pragma("unroll") for (int nn = 0; nn < 4; ++nn)                          \
          acc[mm][nn] = __builtin_amdgcn_mfma_f32_16x16x32_bf16(                \
              av[mm], BV[nn], acc[mm][nn], 0, 0, 0)

// Shared K-loop body. Defines acc[4][4]; caller provides epilogue.
#define GEMM_PREAMBLE_AND_KLOOP()                                               \
  const int tid = threadIdx.x;                                                  \
  const int w = tid >> 6, l = tid & 63;                                         \
  const int wm = w >> 1, wn = w & 1;                                            \
  const int lc = l & 15, lk8 = (l >> 4) * 8;                                    \
  const int nbn = N >> 7;                                                       \
  const int nwg = gridDim.x;                                                    \
  const int q = nwg >> 3, rr = nwg & 7;                                         \
  const int xcd = blockIdx.x & 7, ib = blockIdx.x >> 3;                         \
  const int bswz = (xcd < rr ? xcd * (q + 1) : rr * (q + 1) + (xcd - rr) * q) + ib; \
  const int bm = bswz / nbn, bn = bswz - bm * nbn;                              \
  const unsigned short* Ap = A + (size_t)bm * 256 * K;                          \
  const unsigned short* Bp = Bt + (size_t)bn * 128 * K;                         \
  const int T = K >> 5;                                                         \
  f32x4 acc[4][4] = {};                                                         \
  stage_a(Ap, K, 0, &lds[0][0], tid);                                           \
  stage_b(Bp, K, 0, &lds[0][8192], tid);                                        \
  stage_a(Ap, K, 32, &lds[1][0], tid);                                          \
  stage_b(Bp, K, 32, &lds[1][8192], tid);                                       \
  VMCNT(3);   /* tile0's 3 glds landed; tile1's 3 in flight */                  \
  BARM();                                                                       \
  {                                                                             \
    int s = 0, sp = 2;   /* sp = slot of tile t-1 = target for tile t+2 */      \
    for (int t = 0; t < T; ++t) {                                               \
      const unsigned short* As = &lds[s][0];                                    \
      const unsigned short* Bs = &lds[s][8192];                                 \
      bf16x8 av[4], bq[4];                                                      \
      _Pragma("unroll") for (int mm = 0; mm < 4; ++mm)                          \
          av[mm] = read_frag(As, wm * 64 + mm * 16 + lc, lk8);                  \
      _Pragma("unroll") for (int nn = 0; nn < 4; ++nn)                          \
          bq[nn] = read_frag(Bs, wn * 64 + nn * 16 + lc, lk8);                  \
      if (t + 2 < T) {                                                          \
        stage_a(Ap, K, (t + 2) * 32, &lds[sp][0], tid);                         \
        stage_b(Bp, K, (t + 2) * 32, &lds[sp][8192], tid);                      \
      }                                                                         \
      MFMA16X(bq);                                                              \
      LGKMW();          /* this wave's slot-s reads complete */                 \
      if (t + 2 < T) { VMCNT(3); } else { VMCNT(0); }                           \
      BARM();           /* tile t+1 certified collectively */                   \
      sp = s;                                                                   \
      s = (s == 2) ? 0 : s + 1;                                                 \
    }                                                                           \
  }

__global__ __launch_bounds__(512, 4) void gemm256(
    const unsigned short* __restrict__ A,   // [M][K] bf16
    const unsigned short* __restrict__ Bt,  // [N][K] bf16
    const float* __restrict__ bias,         // [N] f32
    unsigned short* __restrict__ C,         // [M][N] bf16
    int N, int K) {
  __shared__ alignas(16) unsigned short lds[3][12288];   // 73.7 KiB -> 2 blocks/CU
  GEMM_PREAMBLE_AND_KLOOP();

  // ---- epilogue: acc -> LDS [128][136] (padded, 16B-aligned rows) -> dwordx4 ----
  unsigned short* eps = &lds[0][0];   // 128*136*2 = 34.8 KB, fits
  float bv[4];
#pragma unroll
  for (int nn = 0; nn < 4; ++nn) bv[nn] = bias[bn * 128 + wn * 64 + nn * 16 + lc];

#pragma unroll
  for (int r = 0; r < 2; ++r) {
    if ((wm >> 1) == r) {                      // waves wm=2r,2r+1 own rows r*128..+127
#pragma unroll
      for (int mm = 0; mm < 4; ++mm) {
#pragma unroll
        for (int nn = 0; nn < 4; ++nn) {
          int lcol = wn * 64 + nn * 16 + lc;
#pragma unroll
          for (int j = 0; j < 4; ++j) {
            int lrow = (wm & 1) * 64 + mm * 16 + (l >> 4) * 4 + j;
            float v = fmaxf(acc[mm][nn][j] + bv[nn], 0.0f);
            eps[lrow * 136 + lcol] = f2bf(v);
          }
        }
      }
    }
    BARM();
#pragma unroll
    for (int it = 0; it < 4; ++it) {
      int flat = it * 512 + tid;          // 2048 = 128 rows x 16 col-granules
      int lrow = flat >> 4, cb = flat & 15;
      uint4 v = *(const uint4*)&eps[lrow * 136 + cb * 8];
      *(uint4*)&C[(size_t)(bm * 256 + r * 128 + lrow) * N + bn * 128 + cb * 8] = v;
    }
    BARM();
  }
}

// Last layer: identical K-loop; segment-sum relu'd outputs per graph via
// atomicAdd into part[G][N] (batch sorted; pad rows -> sentinel -1).
__global__ __launch_bounds__(512, 4) void gemm_pool(
    const unsigned short* __restrict__ A,   // [M][K] bf16 (chunk base)
    const unsigned short* __restrict__ Bt,  // [N][K] bf16
    const float* __restrict__ bias,         // [N] f32
    const int* __restrict__ batch,          // [Nn] sorted graph ids (global)
    float* __restrict__ part,               // [G][N] f32 accumulators
    int N, int K, int row0, int Nn) {       // row0 = chunk offset in global rows
  __shared__ alignas(16) unsigned short lds[3][12288];
  __shared__ int batchLS[256];
  GEMM_PREAMBLE_AND_KLOOP();

  unsigned short* eps = &lds[0][0];
  if (tid < 256) {
    int grow = row0 + bm * 256 + tid;
    batchLS[tid] = (grow < Nn) ? batch[grow] : -1;
  }
  float bv[4];
#pragma unroll
  for (int nn = 0; nn < 4; ++nn) bv[nn] = bias[bn * 128 + wn * 64 + nn * 16 + lc];

#pragma unroll
  for (int r = 0; r < 2; ++r) {
    if ((wm >> 1) == r) {
#pragma unroll
      for (int mm = 0; mm < 4; ++mm) {
#pragma unroll
        for (int nn = 0; nn < 4; ++nn) {
          int lcol = wn * 64 + nn * 16 + lc;
#pragma unroll
          for (int j = 0; j < 4; ++j) {
            int lrow = (wm & 1) * 64 + mm * 16 + (l >> 4) * 4 + j;
            float v = fmaxf(acc[mm][nn][j] + bv[nn], 0.0f);
            eps[lrow * 136 + lcol] = f2bf(v);
          }
        }
      }
    }
    BARM();
    // column scan: thread -> (col = tid&127, rows qt*32..qt*32+31)
    {
      int col = tid & 127;
      int qt = tid >> 7;                   // 0..3
      int gcur = -2;
      float run = 0.f;
      int gcolbase = bn * 128 + col;
      for (int i = 0; i < 32; ++i) {
        int lr = qt * 32 + i;
        int g = batchLS[r * 128 + lr];
        if (g != gcur) {
          if (gcur >= 0) atomicAdd(&part[(size_t)gcur * N + gcolbase], run);
          gcur = g; run = 0.f;
        }
        run += bf2f(eps[lr * 136 + col]);
      }
      if (gcur >= 0) atomicAdd(&part[(size_t)gcur * N + gcolbase], run);
    }
    BARM();
  }
}

// ---------------- pool finalize ----------------
__global__ void zero_part(float* __restrict__ part, int n) {
  int i = blockIdx.x * blockDim.x + threadIdx.x;
  if (i < n) part[i] = 0.f;
}

__global__ void pool_div(const float* __restrict__ part, const int* __restrict__ batch,
                         float* __restrict__ out, int n, int D, int G) {
  int idx = blockIdx.x * blockDim.x + threadIdx.x;
  if (idx >= G * D) return;
  int g = idx / D;
  int lo, hi;
  { int a = 0, b = n; while (a < b) { int m = (a + b) >> 1; if (batch[m] < g) a = m + 1; else b = m; } lo = a; }
  { int a = lo, b = n; while (a < b) { int m = (a + b) >> 1; if (batch[m] < g + 1) a = m + 1; else b = m; } hi = a; }
  out[idx] = part[idx] / (float)(hi - lo);
}

// ---------------- launcher ----------------
static inline size_t align256(size_t x) { return (x + 255) & ~(size_t)255; }

extern "C" void kernel_launch(void* const* d_in, const int* in_sizes, int n_in,
                              void* d_out, int out_size, void* d_ws, size_t ws_size,
                              hipStream_t stream) {
  const float* x = (const float*)d_in[0];
  // d_in[1] = edge_index (unused by the math)
  const int* batch = (const int*)d_in[2];
  const float* W0 = (const float*)d_in[3];
  const float* b0 = (const float*)d_in[4];
  const float* W1 = (const float*)d_in[5];
  const float* b1 = (const float*)d_in[6];
  const float* W2 = (const float*)d_in[7];
  const float* b2 = (const float*)d_in[8];
  float* out = (float*)d_out;

  const int Nn = in_sizes[2];                 // 100000 nodes
  const int DIN = 512, DH = 1024, DOUT = 512;
  const int G = out_size / DOUT;              // 128
  const int Mpad = ((Nn + 255) / 256) * 256;  // 100096

  // workspace layout
  uint8_t* p = (uint8_t*)d_ws;
  unsigned short* W0t = (unsigned short*)p; p += align256((size_t)DH * DIN * 2);
  unsigned short* W1t = (unsigned short*)p; p += align256((size_t)DH * DH * 2);
  unsigned short* W2t = (unsigned short*)p; p += align256((size_t)DOUT * DH * 2);
  float* part         = (float*)p;          p += align256((size_t)G * DOUT * 4);
  size_t used = (size_t)(p - (uint8_t*)d_ws);
  size_t avail = ws_size > used ? ws_size - used : 0;
  size_t per_row = (size_t)(DIN + DH + DH) * 2;       // xb + h0 + h1 bytes per row
  long long chl = (long long)(avail / per_row);
  chl = (chl / 256) * 256;
  int CH = (int)(chl < 256 ? 256 : chl);
  if (CH > Mpad) CH = Mpad;
  unsigned short* xb = (unsigned short*)p; p += align256((size_t)CH * DIN * 2);
  unsigned short* h0 = (unsigned short*)p; p += align256((size_t)CH * DH * 2);
  unsigned short* h1 = (unsigned short*)p; p += align256((size_t)CH * DH * 2);

  // 0) zero the pooling accumulators
  zero_part<<<dim3((G * DOUT + 255) / 256), 256, 0, stream>>>(part, G * DOUT);

  // 1) weights: transpose + convert to bf16 [N][K]
  transpose_w<<<dim3((DIN / 32) * (DH / 32)), 256, 0, stream>>>(W0, W0t, DIN, DH);
  transpose_w<<<dim3((DH / 32) * (DH / 32)), 256, 0, stream>>>(W1, W1t, DH, DH);
  transpose_w<<<dim3((DH / 32) * (DOUT / 32)), 256, 0, stream>>>(W2, W2t, DH, DOUT);

  // 2) chunked 3-layer MLP (single chunk when ws allows); L2 fuses the pool
  for (int off = 0; off < Mpad; off += CH) {
    int rows = Mpad - off; if (rows > CH) rows = CH;
    int nvalid = Nn - off;
    size_t cvt_threads = (size_t)rows * DIN / 8;
    int cvt_blocks = (int)((cvt_threads + 255) / 256);
    if (cvt_blocks > 2048) cvt_blocks = 2048;
    cvt_x<<<dim3(cvt_blocks), 256, 0, stream>>>(x + (size_t)off * DIN, xb, rows, nvalid, DIN);

    gemm256<<<dim3((rows / 256) * (DH / 128)), 512, 0, stream>>>(xb, W0t, b0, h0, DH, DIN);
    gemm256<<<dim3((rows / 256) * (DH / 128)), 512, 0, stream>>>(h0, W1t, b1, h1, DH, DH);
    gemm_pool<<<dim3((rows / 256) * (DOUT / 128)), 512, 0, stream>>>(
        h1, W2t, b2, batch, part, DOUT, DH, off, Nn);
  }

  // 3) finalize: mean = sum / count
  pool_div<<<dim3((G * DOUT + 255) / 256), 256, 0, stream>>>(part, batch, out, Nn, DOUT, G);
}